// Round 1
// baseline (2560.015 us; speedup 1.0000x reference)
//
#include <hip/hip_runtime.h>
#include <hip/hip_cooperative_groups.h>

namespace cg = cooperative_groups;

static constexpr int KA        = 256;    // dictionary atoms
static constexpr int PIX       = 1024;   // M*M
static constexpr int NBLK      = 512;    // cooperative grid blocks
static constexpr int ROWS      = 8;      // batch rows per block (512*8 = 4096)
static constexpr int NTHR      = 256;
static constexpr int MAX_ITERS = 2048;   // safety cap (deadlock guard)
static constexpr float LR2     = 0.2f;   // 2 * R_LR
static constexpr float LMDA_C  = 0.005f;
static constexpr float TOL2    = 1e-4f;  // TOL^2; num < TOL2*den  <=>  ratio < TOL

// ---------- U [1024x256] -> Ut [256x1024] ----------
__global__ __launch_bounds__(256) void k_transpose(const float* __restrict__ U,
                                                   float* __restrict__ Ut) {
    __shared__ float tile[64 * 65];
    const int bx = blockIdx.x & 3;   // k-tile (0..3)
    const int by = blockIdx.x >> 2;  // m-tile (0..15)
    const int lane = threadIdx.x & 63;
    const int w = threadIdx.x >> 6;
    const int m0 = by * 64, k0 = bx * 64;
    #pragma unroll
    for (int i = 0; i < 16; ++i) {
        const int ml = w * 16 + i;
        tile[lane * 65 + ml] = U[(m0 + ml) * KA + k0 + lane];  // tile[k_local][m_local]
    }
    __syncthreads();
    #pragma unroll
    for (int i = 0; i < 16; ++i) {
        const int kl = w * 16 + i;
        Ut[(k0 + kl) * PIX + m0 + lane] = tile[kl * 65 + lane];
    }
}

// ---------- S = U^T U : block i computes row i ----------
__global__ __launch_bounds__(256) void k_gram(const float* __restrict__ U,
                                              const float* __restrict__ Ut,
                                              float* __restrict__ S) {
    __shared__ float col[PIX];
    const int i = blockIdx.x;
    const int t = threadIdx.x;
    #pragma unroll
    for (int q = 0; q < 4; ++q) col[t + 256 * q] = Ut[i * PIX + t + 256 * q];
    __syncthreads();
    float acc = 0.f;
    for (int p = 0; p < PIX; p += 4) {
        float4 cv = *(const float4*)&col[p];
        acc += cv.x * U[(p + 0) * KA + t];
        acc += cv.y * U[(p + 1) * KA + t];
        acc += cv.z * U[(p + 2) * KA + t];
        acc += cv.w * U[(p + 3) * KA + t];
    }
    S[i * KA + t] = acc;
}

// ---------- persistent cooperative ISTA ----------
// thread t: column group c = t&63 -> cols 4c..4c+3 ; row group rg = t>>6 -> rows 2rg,2rg+1
__global__ __launch_bounds__(NTHR, 2) void k_ista(const float* __restrict__ img,
                                                  const float* __restrict__ U,
                                                  const float* __restrict__ S,
                                                  const float* __restrict__ Ut,
                                                  float* __restrict__ out,
                                                  float* partials) {
    __shared__ float imgT[PIX * ROWS];  // [p][b]  32 KB (prologue only)
    __shared__ float Rsh[KA * ROWS];    // [k][b]   8 KB
    __shared__ float red[16];

    cg::grid_group grid = cg::this_grid();

    const int t = threadIdx.x;
    const int c = t & 63;
    const int rg = t >> 6;
    const int blk = blockIdx.x;
    const int row0 = blk * ROWS;

    // ---- stage this block's 8 img rows, transposed ----
    #pragma unroll
    for (int b = 0; b < ROWS; ++b) {
        const float* src = img + (size_t)(row0 + b) * PIX;
        #pragma unroll
        for (int q = 0; q < 4; ++q) {
            const int p = t + 256 * q;
            imgT[p * ROWS + b] = src[p];
        }
    }
    __syncthreads();

    // ---- G = img @ U  (this thread's 2x4 tile, kept in registers) ----
    float G0[4] = {0.f, 0.f, 0.f, 0.f}, G1[4] = {0.f, 0.f, 0.f, 0.f};
    {
        const float* Up = U + (c << 2);
        #pragma unroll 4
        for (int p = 0; p < PIX; ++p) {
            float2 iv = *(const float2*)&imgT[p * ROWS + (rg << 1)];
            float4 uv = *(const float4*)&Up[p * KA];
            G0[0] += iv.x * uv.x; G0[1] += iv.x * uv.y; G0[2] += iv.x * uv.z; G0[3] += iv.x * uv.w;
            G1[0] += iv.y * uv.x; G1[1] += iv.y * uv.y; G1[2] += iv.y * uv.z; G1[3] += iv.y * uv.w;
        }
    }

    // ---- R = 0 ----
    float R0[4] = {0.f, 0.f, 0.f, 0.f}, R1[4] = {0.f, 0.f, 0.f, 0.f};
    #pragma unroll
    for (int q = 0; q < 8; ++q) Rsh[t + 256 * q] = 0.f;
    __syncthreads();

    // ---- ISTA loop ----
    for (int iter = 0; iter < MAX_ITERS; ++iter) {
        // dots: a[b][i] = sum_j R[b][j] * S[j][k]
        float a0[4] = {0.f, 0.f, 0.f, 0.f}, a1[4] = {0.f, 0.f, 0.f, 0.f};
        const float* Sp = S + (c << 2);
        #pragma unroll 4
        for (int j = 0; j < KA; ++j) {
            float2 rv = *(const float2*)&Rsh[j * ROWS + (rg << 1)];  // LDS broadcast
            float4 sv = *(const float4*)&Sp[j * KA];                 // L2-resident
            a0[0] += rv.x * sv.x; a0[1] += rv.x * sv.y; a0[2] += rv.x * sv.z; a0[3] += rv.x * sv.w;
            a1[0] += rv.y * sv.x; a1[1] += rv.y * sv.y; a1[2] += rv.y * sv.z; a1[3] += rv.y * sv.w;
        }
        __syncthreads();  // all dot-reads of Rsh done before overwrite

        float num = 0.f, den = 0.f;
        #pragma unroll
        for (int i = 0; i < 4; ++i) {
            const float v0 = R0[i] + LR2 * (G0[i] - a0[i]);
            const float v1 = R1[i] + LR2 * (G1[i] - a1[i]);
            const float n0 = fmaxf(v0 - LMDA_C, 0.f) - fmaxf(-v0 - LMDA_C, 0.f);
            const float n1 = fmaxf(v1 - LMDA_C, 0.f) - fmaxf(-v1 - LMDA_C, 0.f);
            const float d0 = n0 - R0[i], d1 = n1 - R1[i];
            num += d0 * d0 + d1 * d1;
            den += R0[i] * R0[i] + R1[i] * R1[i];
            R0[i] = n0; R1[i] = n1;
            *(float2*)&Rsh[((c << 2) + i) * ROWS + (rg << 1)] = make_float2(n0, n1);
        }

        // block reduce (4 waves)
        #pragma unroll
        for (int off = 32; off > 0; off >>= 1) {
            num += __shfl_down(num, off, 64);
            den += __shfl_down(den, off, 64);
        }
        if (c == 0) { red[rg * 2] = num; red[rg * 2 + 1] = den; }
        __syncthreads();
        const int par = iter & 1;
        if (t == 0) {
            const float n = red[0] + red[2] + red[4] + red[6];
            const float d = red[1] + red[3] + red[5] + red[7];
            __hip_atomic_store(&partials[par * (2 * NBLK) + blk * 2 + 0], n,
                               __ATOMIC_RELAXED, __HIP_MEMORY_SCOPE_AGENT);
            __hip_atomic_store(&partials[par * (2 * NBLK) + blk * 2 + 1], d,
                               __ATOMIC_RELAXED, __HIP_MEMORY_SCOPE_AGENT);
        }
        __threadfence();
        grid.sync();

        // every block reduces all 512 partials identically -> uniform decision
        if (t < 64) {
            float n = 0.f, d = 0.f;
            #pragma unroll
            for (int q = 0; q < NBLK / 64; ++q) {
                const int bi = t * (NBLK / 64) + q;
                n += __hip_atomic_load(&partials[par * (2 * NBLK) + bi * 2 + 0],
                                       __ATOMIC_RELAXED, __HIP_MEMORY_SCOPE_AGENT);
                d += __hip_atomic_load(&partials[par * (2 * NBLK) + bi * 2 + 1],
                                       __ATOMIC_RELAXED, __HIP_MEMORY_SCOPE_AGENT);
            }
            #pragma unroll
            for (int off = 32; off > 0; off >>= 1) {
                n += __shfl_down(n, off, 64);
                d += __shfl_down(d, off, 64);
            }
            if (t == 0) red[8] = (n < TOL2 * d) ? 1.f : 0.f;
        }
        __syncthreads();
        if (red[8] != 0.f) break;  // uniform across grid
    }

    // ---- out = R @ U^T  (Rsh holds converged R) ----
    __syncthreads();
    #pragma unroll
    for (int q = 0; q < 4; ++q) {
        float p0[4] = {0.f, 0.f, 0.f, 0.f}, p1[4] = {0.f, 0.f, 0.f, 0.f};
        const float* Utp = Ut + q * 256 + (c << 2);
        #pragma unroll 4
        for (int k = 0; k < KA; ++k) {
            float2 rv = *(const float2*)&Rsh[k * ROWS + (rg << 1)];
            float4 uv = *(const float4*)&Utp[k * PIX];
            p0[0] += rv.x * uv.x; p0[1] += rv.x * uv.y; p0[2] += rv.x * uv.z; p0[3] += rv.x * uv.w;
            p1[0] += rv.y * uv.x; p1[1] += rv.y * uv.y; p1[2] += rv.y * uv.z; p1[3] += rv.y * uv.w;
        }
        const size_t o0 = (size_t)(row0 + (rg << 1) + 0) * PIX + q * 256 + (c << 2);
        const size_t o1 = (size_t)(row0 + (rg << 1) + 1) * PIX + q * 256 + (c << 2);
        *(float4*)&out[o0] = make_float4(p0[0], p0[1], p0[2], p0[3]);
        *(float4*)&out[o1] = make_float4(p1[0], p1[1], p1[2], p1[3]);
    }
}

extern "C" void kernel_launch(void* const* d_in, const int* in_sizes, int n_in,
                              void* d_out, int out_size, void* d_ws, size_t ws_size,
                              hipStream_t stream) {
    const float* img = (const float*)d_in[0];  // [4096, 1024]
    const float* U   = (const float*)d_in[1];  // [1024, 256]
    float* out = (float*)d_out;                // [4096, 1024]
    float* ws  = (float*)d_ws;

    float* Ut       = ws;                      // 256*1024 floats (1 MB)
    float* S        = ws + 262144;             // 256*256 floats (256 KB)
    float* partials = ws + 262144 + 65536;     // 2 * 512 * 2 floats

    k_transpose<<<64, 256, 0, stream>>>(U, Ut);
    k_gram<<<256, 256, 0, stream>>>(U, Ut, S);

    void* args[] = {(void*)&img, (void*)&U, (void*)&S, (void*)&Ut, (void*)&out, (void*)&partials};
    hipLaunchCooperativeKernel((void*)k_ista, dim3(NBLK), dim3(NTHR), args, 0, stream);
}

// Round 2
// 672.699 us; speedup vs baseline: 3.8056x; 3.8056x over previous
//
#include <hip/hip_runtime.h>

static constexpr int KA        = 256;    // dictionary atoms
static constexpr int PIX       = 1024;   // M*M
static constexpr int NBLK      = 512;    // grid blocks (co-resident, 2/CU)
static constexpr int ROWS      = 8;      // batch rows per block
static constexpr int NTHR      = 256;
static constexpr int MAX_ITERS = 2048;   // safety cap
static constexpr float LR2     = 0.2f;   // 2 * R_LR
static constexpr float LMDA_C  = 0.005f;
static constexpr float TOL2    = 1e-4f;  // TOL^2

// ---------- U [1024x256] -> Ut [256x1024]  (+ zero the barrier flags) ----------
__global__ __launch_bounds__(256) void k_transpose(const float* __restrict__ U,
                                                   float* __restrict__ Ut,
                                                   int* __restrict__ flags) {
    const int g = blockIdx.x * 256 + threadIdx.x;
    if (g < NBLK) flags[g] = 0;

    __shared__ float tile[64 * 65];
    const int bx = blockIdx.x & 3;   // k-tile
    const int by = blockIdx.x >> 2;  // m-tile
    const int lane = threadIdx.x & 63;
    const int w = threadIdx.x >> 6;
    const int m0 = by * 64, k0 = bx * 64;
    #pragma unroll
    for (int i = 0; i < 16; ++i) {
        const int ml = w * 16 + i;
        tile[lane * 65 + ml] = U[(m0 + ml) * KA + k0 + lane];
    }
    __syncthreads();
    #pragma unroll
    for (int i = 0; i < 16; ++i) {
        const int kl = w * 16 + i;
        Ut[(k0 + kl) * PIX + m0 + lane] = tile[kl * 65 + lane];
    }
}

// ---------- S = U^T U : block i computes row i ----------
__global__ __launch_bounds__(256) void k_gram(const float* __restrict__ U,
                                              const float* __restrict__ Ut,
                                              float* __restrict__ S) {
    __shared__ float col[PIX];
    const int i = blockIdx.x;
    const int t = threadIdx.x;
    #pragma unroll
    for (int q = 0; q < 4; ++q) col[t + 256 * q] = Ut[i * PIX + t + 256 * q];
    __syncthreads();
    float acc = 0.f;
    for (int p = 0; p < PIX; p += 4) {
        float4 cv = *(const float4*)&col[p];
        acc += cv.x * U[(p + 0) * KA + t];
        acc += cv.y * U[(p + 1) * KA + t];
        acc += cv.z * U[(p + 2) * KA + t];
        acc += cv.w * U[(p + 3) * KA + t];
    }
    S[i * KA + t] = acc;
}

// ---------- persistent ISTA, fence-free flag barrier ----------
// thread t: c = t&63 -> cols 4c..4c+3 ; rg = t>>6 -> j-slice [64rg,64rg+64)
// final ownership: rows 2rg, 2rg+1  x  cols 4c..4c+3
__global__ __launch_bounds__(NTHR, 2) void k_ista(const float* __restrict__ img,
                                                  const float* __restrict__ U,
                                                  const float* __restrict__ S,
                                                  const float* __restrict__ Ut,
                                                  float* __restrict__ out,
                                                  float* partials, int* flags) {
    __shared__ float part[4 * ROWS * KA];  // 32 KB: imgT in prologue, split-j partials after
    __shared__ float Rsh[KA * ROWS];       // 8 KB, layout [k][b]
    __shared__ float red[16];

    const int t = threadIdx.x;
    const int c = t & 63;
    const int rg = t >> 6;
    const int blk = blockIdx.x;
    const int row0 = blk * ROWS;

    // ---- stage img rows transposed into part ([p][b], stride 8) ----
    #pragma unroll
    for (int b = 0; b < ROWS; ++b) {
        const float* src = img + (size_t)(row0 + b) * PIX;
        #pragma unroll
        for (int q = 0; q < 4; ++q) {
            const int p = t + 256 * q;
            part[p * ROWS + b] = src[p];
        }
    }
    __syncthreads();

    // ---- G = img @ U, split over p (each rg owns 256 of 1024) ----
    float Ga[8][4];
    #pragma unroll
    for (int b = 0; b < 8; ++b)
        #pragma unroll
        for (int i = 0; i < 4; ++i) Ga[b][i] = 0.f;
    {
        const float* Up = U + (size_t)(rg * 256) * KA + (c << 2);
        const float* Ip = part + rg * 256 * ROWS;
        #pragma unroll 4
        for (int p = 0; p < 256; ++p) {
            float4 r0 = *(const float4*)&Ip[p * ROWS];
            float4 r1 = *(const float4*)&Ip[p * ROWS + 4];
            float4 uv = *(const float4*)&Up[(size_t)p * KA];
            Ga[0][0] += r0.x * uv.x; Ga[0][1] += r0.x * uv.y; Ga[0][2] += r0.x * uv.z; Ga[0][3] += r0.x * uv.w;
            Ga[1][0] += r0.y * uv.x; Ga[1][1] += r0.y * uv.y; Ga[1][2] += r0.y * uv.z; Ga[1][3] += r0.y * uv.w;
            Ga[2][0] += r0.z * uv.x; Ga[2][1] += r0.z * uv.y; Ga[2][2] += r0.z * uv.z; Ga[2][3] += r0.z * uv.w;
            Ga[3][0] += r0.w * uv.x; Ga[3][1] += r0.w * uv.y; Ga[3][2] += r0.w * uv.z; Ga[3][3] += r0.w * uv.w;
            Ga[4][0] += r1.x * uv.x; Ga[4][1] += r1.x * uv.y; Ga[4][2] += r1.x * uv.z; Ga[4][3] += r1.x * uv.w;
            Ga[5][0] += r1.y * uv.x; Ga[5][1] += r1.y * uv.y; Ga[5][2] += r1.y * uv.z; Ga[5][3] += r1.y * uv.w;
            Ga[6][0] += r1.z * uv.x; Ga[6][1] += r1.z * uv.y; Ga[6][2] += r1.z * uv.z; Ga[6][3] += r1.z * uv.w;
            Ga[7][0] += r1.w * uv.x; Ga[7][1] += r1.w * uv.y; Ga[7][2] += r1.w * uv.z; Ga[7][3] += r1.w * uv.w;
        }
    }
    __syncthreads();  // done reading imgT from part
    {
        float* pw = part + rg * (ROWS * KA) + (c << 2);
        #pragma unroll
        for (int b = 0; b < 8; ++b)
            *(float4*)&pw[b * KA] = make_float4(Ga[b][0], Ga[b][1], Ga[b][2], Ga[b][3]);
    }
    __syncthreads();
    float G0[4], G1[4];
    {
        #pragma unroll
        for (int i = 0; i < 4; ++i) { G0[i] = 0.f; G1[i] = 0.f; }
        const float* pr = part + (rg << 1) * KA + (c << 2);
        #pragma unroll
        for (int rr = 0; rr < 4; ++rr) {
            float4 v0 = *(const float4*)&pr[rr * (ROWS * KA)];
            float4 v1 = *(const float4*)&pr[rr * (ROWS * KA) + KA];
            G0[0] += v0.x; G0[1] += v0.y; G0[2] += v0.z; G0[3] += v0.w;
            G1[0] += v1.x; G1[1] += v1.y; G1[2] += v1.z; G1[3] += v1.w;
        }
    }

    // ---- R = 0 ----
    float R0[4] = {0.f, 0.f, 0.f, 0.f}, R1[4] = {0.f, 0.f, 0.f, 0.f};
    #pragma unroll
    for (int q = 0; q < 8; ++q) Rsh[t + 256 * q] = 0.f;
    __syncthreads();

    // ---- ISTA loop ----
    for (int iter = 0; iter < MAX_ITERS; ++iter) {
        // split-j dot: a[b][i] partial over j in [64rg, 64rg+64)
        float a[8][4];
        #pragma unroll
        for (int b = 0; b < 8; ++b)
            #pragma unroll
            for (int i = 0; i < 4; ++i) a[b][i] = 0.f;
        {
            const float* Sp = S + (size_t)(rg * 64) * KA + (c << 2);
            const float* Rp = Rsh + rg * 64 * ROWS;
            #pragma unroll 4
            for (int jj = 0; jj < 64; ++jj) {
                float4 r0 = *(const float4*)&Rp[jj * ROWS];
                float4 r1 = *(const float4*)&Rp[jj * ROWS + 4];
                float4 sv = *(const float4*)&Sp[(size_t)jj * KA];
                a[0][0] += r0.x * sv.x; a[0][1] += r0.x * sv.y; a[0][2] += r0.x * sv.z; a[0][3] += r0.x * sv.w;
                a[1][0] += r0.y * sv.x; a[1][1] += r0.y * sv.y; a[1][2] += r0.y * sv.z; a[1][3] += r0.y * sv.w;
                a[2][0] += r0.z * sv.x; a[2][1] += r0.z * sv.y; a[2][2] += r0.z * sv.z; a[2][3] += r0.z * sv.w;
                a[3][0] += r0.w * sv.x; a[3][1] += r0.w * sv.y; a[3][2] += r0.w * sv.z; a[3][3] += r0.w * sv.w;
                a[4][0] += r1.x * sv.x; a[4][1] += r1.x * sv.y; a[4][2] += r1.x * sv.z; a[4][3] += r1.x * sv.w;
                a[5][0] += r1.y * sv.x; a[5][1] += r1.y * sv.y; a[5][2] += r1.y * sv.z; a[5][3] += r1.y * sv.w;
                a[6][0] += r1.z * sv.x; a[6][1] += r1.z * sv.y; a[6][2] += r1.z * sv.z; a[6][3] += r1.z * sv.w;
                a[7][0] += r1.w * sv.x; a[7][1] += r1.w * sv.y; a[7][2] += r1.w * sv.z; a[7][3] += r1.w * sv.w;
            }
        }
        {
            float* pw = part + rg * (ROWS * KA) + (c << 2);
            #pragma unroll
            for (int b = 0; b < 8; ++b)
                *(float4*)&pw[b * KA] = make_float4(a[b][0], a[b][1], a[b][2], a[b][3]);
        }
        __syncthreads();  // partials visible; all Rsh dot-reads complete
        float a0[4] = {0.f, 0.f, 0.f, 0.f}, a1[4] = {0.f, 0.f, 0.f, 0.f};
        {
            const float* pr = part + (rg << 1) * KA + (c << 2);
            #pragma unroll
            for (int rr = 0; rr < 4; ++rr) {
                float4 v0 = *(const float4*)&pr[rr * (ROWS * KA)];
                float4 v1 = *(const float4*)&pr[rr * (ROWS * KA) + KA];
                a0[0] += v0.x; a0[1] += v0.y; a0[2] += v0.z; a0[3] += v0.w;
                a1[0] += v1.x; a1[1] += v1.y; a1[2] += v1.z; a1[3] += v1.w;
            }
        }

        float num = 0.f, den = 0.f;
        #pragma unroll
        for (int i = 0; i < 4; ++i) {
            const float v0 = R0[i] + LR2 * (G0[i] - a0[i]);
            const float v1 = R1[i] + LR2 * (G1[i] - a1[i]);
            const float n0 = fmaxf(v0 - LMDA_C, 0.f) - fmaxf(-v0 - LMDA_C, 0.f);
            const float n1 = fmaxf(v1 - LMDA_C, 0.f) - fmaxf(-v1 - LMDA_C, 0.f);
            const float d0 = n0 - R0[i], d1 = n1 - R1[i];
            num += d0 * d0 + d1 * d1;
            den += R0[i] * R0[i] + R1[i] * R1[i];
            R0[i] = n0; R1[i] = n1;
            *(float2*)&Rsh[((c << 2) + i) * ROWS + (rg << 1)] = make_float2(n0, n1);
        }

        // wave reduce, then block reduce into red[]
        #pragma unroll
        for (int off = 32; off > 0; off >>= 1) {
            num += __shfl_down(num, off, 64);
            den += __shfl_down(den, off, 64);
        }
        if (c == 0) { red[rg * 2] = num; red[rg * 2 + 1] = den; }
        __syncthreads();

        const int par = iter & 1;
        if (t == 0) {
            const float n = red[0] + red[2] + red[4] + red[6];
            const float d = red[1] + red[3] + red[5] + red[7];
            __hip_atomic_store(&partials[par * (2 * NBLK) + blk * 2 + 0], n,
                               __ATOMIC_RELAXED, __HIP_MEMORY_SCOPE_AGENT);
            __hip_atomic_store(&partials[par * (2 * NBLK) + blk * 2 + 1], d,
                               __ATOMIC_RELAXED, __HIP_MEMORY_SCOPE_AGENT);
            __builtin_amdgcn_s_waitcnt(0);  // partial stores at coherence point before flag bump
            __hip_atomic_fetch_add(&flags[blk], 1, __ATOMIC_RELAXED, __HIP_MEMORY_SCOPE_AGENT);
        }
        // fence-free barrier: wait until all 512 blocks posted this iteration
        if (t < 64) {
            #pragma unroll 1
            for (int q = 0; q < 8; ++q) {
                const int bi = t * 8 + q;
                while (__hip_atomic_load(&flags[bi], __ATOMIC_RELAXED,
                                         __HIP_MEMORY_SCOPE_AGENT) <= iter)
                    __builtin_amdgcn_s_sleep(1);
            }
        }
        __syncthreads();
        // every block reduces all 512 partials identically -> uniform decision
        if (t < 64) {
            float n = 0.f, d = 0.f;
            #pragma unroll
            for (int q = 0; q < 8; ++q) {
                const int bi = t * 8 + q;
                n += __hip_atomic_load(&partials[par * (2 * NBLK) + bi * 2 + 0],
                                       __ATOMIC_RELAXED, __HIP_MEMORY_SCOPE_AGENT);
                d += __hip_atomic_load(&partials[par * (2 * NBLK) + bi * 2 + 1],
                                       __ATOMIC_RELAXED, __HIP_MEMORY_SCOPE_AGENT);
            }
            #pragma unroll
            for (int off = 32; off > 0; off >>= 1) {
                n += __shfl_down(n, off, 64);
                d += __shfl_down(d, off, 64);
            }
            if (t == 0) red[8] = (n < TOL2 * d) ? 1.f : 0.f;
        }
        __syncthreads();
        if (red[8] != 0.f) break;  // uniform across grid
    }

    // ---- out = R @ U^T ----
    __syncthreads();
    #pragma unroll
    for (int q = 0; q < 4; ++q) {
        float p0[4] = {0.f, 0.f, 0.f, 0.f}, p1[4] = {0.f, 0.f, 0.f, 0.f};
        const float* Utp = Ut + q * 256 + (c << 2);
        #pragma unroll 4
        for (int k = 0; k < KA; ++k) {
            float2 rv = *(const float2*)&Rsh[k * ROWS + (rg << 1)];
            float4 uv = *(const float4*)&Utp[(size_t)k * PIX];
            p0[0] += rv.x * uv.x; p0[1] += rv.x * uv.y; p0[2] += rv.x * uv.z; p0[3] += rv.x * uv.w;
            p1[0] += rv.y * uv.x; p1[1] += rv.y * uv.y; p1[2] += rv.y * uv.z; p1[3] += rv.y * uv.w;
        }
        const size_t o0 = (size_t)(row0 + (rg << 1) + 0) * PIX + q * 256 + (c << 2);
        const size_t o1 = (size_t)(row0 + (rg << 1) + 1) * PIX + q * 256 + (c << 2);
        *(float4*)&out[o0] = make_float4(p0[0], p0[1], p0[2], p0[3]);
        *(float4*)&out[o1] = make_float4(p1[0], p1[1], p1[2], p1[3]);
    }
}

extern "C" void kernel_launch(void* const* d_in, const int* in_sizes, int n_in,
                              void* d_out, int out_size, void* d_ws, size_t ws_size,
                              hipStream_t stream) {
    const float* img = (const float*)d_in[0];  // [4096, 1024]
    const float* U   = (const float*)d_in[1];  // [1024, 256]
    float* out = (float*)d_out;                // [4096, 1024]
    float* ws  = (float*)d_ws;

    float* Ut       = ws;                        // 262144 floats
    float* S        = ws + 262144;               // 65536 floats
    float* partials = ws + 262144 + 65536;       // 2048 floats
    int*   flags    = (int*)(ws + 262144 + 65536 + 2048);  // 512 ints

    k_transpose<<<64, 256, 0, stream>>>(U, Ut, flags);
    k_gram<<<256, 256, 0, stream>>>(U, Ut, S);

    void* args[] = {(void*)&img, (void*)&U, (void*)&S, (void*)&Ut,
                    (void*)&out, (void*)&partials, (void*)&flags};
    hipLaunchCooperativeKernel((void*)k_ista, dim3(NBLK), dim3(NTHR), args, 0, stream);
}